// Round 3
// baseline (470.294 us; speedup 1.0000x reference)
//
#include <hip/hip_runtime.h>
#include <hip/hip_bf16.h>
#include <stdint.h>

typedef __attribute__((ext_vector_type(8))) short short8;
typedef __attribute__((ext_vector_type(4))) float f32x4;

__device__ __forceinline__ unsigned pack_bf2(float a, float b) {
  union { __hip_bfloat162 h2; unsigned u; } cv;
  cv.h2 = __float22bfloat162_rn(make_float2(a, b));
  return cv.u;
}

__device__ __forceinline__ short8 pack8(const f32x4& a, const f32x4& b) {
  union { unsigned u[4]; short8 s; } cv;
  cv.u[0] = pack_bf2(a.x, a.y); cv.u[1] = pack_bf2(a.z, a.w);
  cv.u[2] = pack_bf2(b.x, b.y); cv.u[3] = pack_bf2(b.z, b.w);
  return cv.s;
}

// B packed in MFMA-fragment order: WB[((kt*16+g)*2+ks)*64 + l] = 16B holding
// B[col = g*16 + (l&15)][kk = kt*64 + ks*32 + (l>>4)*8 + j], j=0..7.
// col n -> (c = n>>1, n&1 ? W2 : W1); kk -> (k = kk>>3, e = kk&7).
__global__ void pack_w(const float* __restrict__ W1, const float* __restrict__ W2,
                       __hip_bfloat16* __restrict__ WB) {
  int idx = blockIdx.x * 256 + threadIdx.x;   // 1<<20 elements
  int j  = idx & 7;
  int l  = (idx >> 3) & 63;
  int ks = (idx >> 9) & 1;
  int g  = (idx >> 10) & 15;
  int kt = idx >> 14;
  int lr = l & 15, lk = l >> 4;
  int col = g * 16 + lr;
  int kk = kt * 64 + ks * 32 + lk * 8 + j;
  int c = col >> 1;
  const float* W = (col & 1) ? W2 : W1;
  WB[idx] = __float2bfloat16(W[(c * 8 + (kk & 7)) * 512 + (kk >> 3)]);
}

#define LOADA(dst, kt_) do { \
  _Pragma("unroll") \
  for (int mi = 0; mi < 2; ++mi) \
    _Pragma("unroll") \
    for (int ks = 0; ks < 2; ++ks) \
      _Pragma("unroll") \
      for (int hf = 0; hf < 2; ++hf) \
        dst[mi*4+ks*2+hf] = *(const f32x4*)(abase + \
            ((size_t)(kt_) * 64 + (size_t)mi * 16 * 4096 + ks * 32 + hf * 4) * 4); \
} while (0)

#define LOADB(dst, kt_) do { \
  _Pragma("unroll") \
  for (int nj = 0; nj < 4; ++nj) \
    _Pragma("unroll") \
    for (int ks = 0; ks < 2; ++ks) \
      dst[nj*2+ks] = *(const short8*)(bbase + \
          (size_t)(kt_) * 32768 + nj * 2048 + ks * 1024); \
} while (0)

#define COMPUTE(a_, b_) do { \
  short8 af[2][2]; \
  _Pragma("unroll") \
  for (int mi = 0; mi < 2; ++mi) \
    _Pragma("unroll") \
    for (int ks = 0; ks < 2; ++ks) \
      af[mi][ks] = pack8(a_[mi*4+ks*2], a_[mi*4+ks*2+1]); \
  _Pragma("unroll") \
  for (int mi = 0; mi < 2; ++mi) \
    _Pragma("unroll") \
    for (int nj = 0; nj < 4; ++nj) \
      _Pragma("unroll") \
      for (int ks = 0; ks < 2; ++ks) \
        acc[mi][nj] = __builtin_amdgcn_mfma_f32_16x16x32_bf16( \
            af[mi][ks], b_[nj*2+ks], acc[mi][nj], 0, 0, 0); \
} while (0)

// Block: 64 rows x 128 cols, 4 waves (2M x 2N), wave tile 32x64.
// Barrier-free, LDS-free: A global->reg->cvt, B global->reg (fragment-ordered).
__global__ __launch_bounds__(256, 2) void gemm_gate(
    const float* __restrict__ z, const __hip_bfloat16* __restrict__ WB,
    const float* __restrict__ b1, const float* __restrict__ b2,
    float* __restrict__ partial) {
  const int t = threadIdx.x;
  const int l = t & 63, w = t >> 6;
  const int wm = w >> 1, wn = w & 1;
  const int lr = l & 15;

  // XCD-chunked swizzle: both N-halves of an M-tile land on one XCD (z L2 reuse)
  const int h = blockIdx.x;
  const int logical = (h & 7) * 64 + (h >> 3);
  const int mb = logical >> 1, nh = logical & 1;
  const int rowbase = mb * 64 + wm * 32;

  const char* abase = (const char*)(z + (size_t)(rowbase + lr) * 4096 + (l >> 4) * 8);
  const int gbase = nh * 8 + wn * 4;
  const char* bbase = (const char*)WB + (size_t)gbase * 2048 + (size_t)l * 16;

  f32x4 acc[2][4];
#pragma unroll
  for (int i = 0; i < 2; ++i)
#pragma unroll
    for (int j = 0; j < 4; ++j) acc[i][j] = (f32x4)0.0f;

  f32x4 aE[8], aO[8];
  short8 bE[8], bO[8];

  LOADA(aE, 0); LOADB(bE, 0);
#pragma unroll 1
  for (int kt = 0; kt < 62; kt += 2) {
    LOADA(aO, kt + 1); LOADB(bO, kt + 1);
    COMPUTE(aE, bE);
    LOADA(aE, kt + 2); LOADB(bE, kt + 2);
    COMPUTE(aO, bO);
  }
  LOADA(aO, 63); LOADB(bO, 63);
  COMPUTE(aE, bE);
  COMPUTE(aO, bO);

  // Epilogue: gate + max over this wave's 32 rows.
  // C layout: col = lane&15 (N), row = (lane>>4)*4 + reg (M).
#pragma unroll
  for (int nj = 0; nj < 4; ++nj) {
    const int c = nh * 64 + wn * 32 + nj * 8 + (lr >> 1);
    const float vb1 = b1[c], vb2 = b2[c];
    float gm = -3.4e38f;
#pragma unroll
    for (int mi = 0; mi < 2; ++mi) {
#pragma unroll
      for (int rr = 0; rr < 4; ++rr) {
        float v = acc[mi][nj][rr];
        float p = __shfl_xor(v, 1, 64);
        float c1 = (lr & 1) ? p : v;
        float c2 = (lr & 1) ? v : p;
        c1 += vb1; c2 += vb2;
        float g = c1 * (1.0f / (1.0f + __expf(-c2)));
        gm = fmaxf(gm, g);
      }
    }
    gm = fmaxf(gm, __shfl_xor(gm, 16, 64));
    gm = fmaxf(gm, __shfl_xor(gm, 32, 64));
    if ((l < 16) && !(l & 1))
      partial[(size_t)(mb * 2 + wm) * 128 + c] = gm;
  }
}

__global__ void reduce_max(const float* __restrict__ partial, float* __restrict__ out) {
  int idx = blockIdx.x * 256 + threadIdx.x;
  if (idx >= 1024) return;
  int b = idx >> 7, c = idx & 127;
  float m = -3.4e38f;
#pragma unroll 8
  for (int g = 0; g < 64; ++g)
    m = fmaxf(m, partial[(size_t)(b * 64 + g) * 128 + c]);
  out[idx] = m;
}

extern "C" void kernel_launch(void* const* d_in, const int* in_sizes, int n_in,
                              void* d_out, int out_size, void* d_ws, size_t ws_size,
                              hipStream_t stream) {
  const float* z  = (const float*)d_in[0];
  const float* W1 = (const float*)d_in[1];
  const float* b1 = (const float*)d_in[2];
  const float* W2 = (const float*)d_in[3];
  const float* b2 = (const float*)d_in[4];
  float* out = (float*)d_out;

  __hip_bfloat16* WB = (__hip_bfloat16*)d_ws;                    // 2 MB
  float* partial = (float*)((char*)d_ws + 2 * 1024 * 1024);      // 256 KB

  pack_w<<<4096, 256, 0, stream>>>(W1, W2, WB);
  gemm_gate<<<512, 256, 0, stream>>>(z, WB, b1, b2, partial);
  reduce_max<<<4, 256, 0, stream>>>(partial, out);
}